// Round 7
// baseline (173.789 us; speedup 1.0000x reference)
//
#include <hip/hip_runtime.h>
#include <math.h>

#define NQ 4
#define NL 2
#define DIM 16          // 2^NQ
#define BATCH 16
#define CH 256
#define HW 16384        // 128*128
#define SPB 4           // slices per block in fused kernel
#define NBLK (BATCH * CH / SPB)   // 1024 blocks

typedef float floatx4 __attribute__((ext_vector_type(4)));

// ---------------- Kernel 1: per-(b,c) mean over H*W ----------------
__global__ void pool_kernel(const float* __restrict__ x, float* __restrict__ pooled) {
    const int bc = blockIdx.x;                       // 0..4095
    const floatx4* x4 = (const floatx4*)(x + (size_t)bc * HW);
    const int tid = threadIdx.x;                     // 256 threads
    float s = 0.f;
#pragma unroll
    for (int k = 0; k < 16; ++k) {                   // 16 float4 / thread
        floatx4 v = __builtin_nontemporal_load(&x4[tid + k * 256]);
        s += v.x + v.y + v.z + v.w;
    }
#pragma unroll
    for (int off = 32; off > 0; off >>= 1) s += __shfl_down(s, off, 64);
    __shared__ float partial[4];
    if ((tid & 63) == 0) partial[tid >> 6] = s;
    __syncthreads();
    if (tid == 0)
        pooled[bc] = (partial[0] + partial[1] + partial[2] + partial[3]) * (1.0f / HW);
}

// ------- Kernel 2: fused gate (redundant per block) + scale -------
// 1024 blocks x 256 threads; block owns 4 consecutive (b,c) slices (same b).
// Each block redundantly computes z (one wave per qubit), the 16-state
// circuit (thread 0, ~1500 FLOP), and its 4 gates -- ~1 us, fully parallel
// across blocks -- then streams its 256 KB with nt loads/stores.
__global__ void fused_gate_scale(
    const float* __restrict__ x,
    const float* __restrict__ enc_w,   // [NQ, CH]
    const float* __restrict__ enc_b,   // [NQ]
    const float* __restrict__ qw,      // [NL, NQ, 3]
    const float* __restrict__ proj_w,  // [CH, NQ]
    const float* __restrict__ proj_b,  // [CH]
    const float* __restrict__ pooled,  // [BATCH*CH]
    float* __restrict__ out)
{
    const int tid = threadIdx.x;
    const int slice0 = blockIdx.x * SPB;   // 4 consecutive (b,c), same b
    const int b = slice0 >> 8;             // / CH

    __shared__ float sz[NQ];
    __shared__ float sevs[NQ];
    __shared__ float sgate[SPB];

    // z[q] = tanh(dot(pooled[b,:], enc_w[q,:]) + enc_b[q]); one wave per qubit
    {
        const int wid = tid >> 6, lane = tid & 63;
        const float* prow = pooled + b * CH;
        float acc = 0.f;
#pragma unroll
        for (int j = 0; j < 4; ++j) {
            const int c = lane * 4 + j;
            acc += prow[c] * enc_w[wid * CH + c];
        }
#pragma unroll
        for (int off = 32; off > 0; off >>= 1) acc += __shfl_down(acc, off, 64);
        if (lane == 0) sz[wid] = tanhf(acc + enc_b[wid]);
    }
    __syncthreads();

    // 4-qubit statevector on thread 0
    if (tid == 0) {
        float re[DIM], im[DIM];
#pragma unroll
        for (int i = 0; i < DIM; ++i) { re[i] = 0.f; im[i] = 0.f; }
        re[0] = 1.f;

        // AngleEmbedding: RY(z_w) on wire w (wire 0 = MSB)
        for (int w = 0; w < NQ; ++w) {
            const float a = sz[w] * 0.5f;
            const float cc = cosf(a), ss = sinf(a);
            const int m = 1 << (3 - w);
#pragma unroll
            for (int i = 0; i < DIM; ++i) {
                if (i & m) continue;
                const int j = i | m;
                const float r0 = cc * re[i] - ss * re[j];
                const float i0 = cc * im[i] - ss * im[j];
                const float r1 = ss * re[i] + cc * re[j];
                const float i1 = ss * im[i] + cc * im[j];
                re[i] = r0; im[i] = i0; re[j] = r1; im[j] = i1;
            }
        }

        // StronglyEntanglingLayers
        for (int l = 0; l < NL; ++l) {
            for (int w = 0; w < NQ; ++w) {
                const float phi = qw[(l * NQ + w) * 3 + 0];
                const float th  = qw[(l * NQ + w) * 3 + 1];
                const float om  = qw[(l * NQ + w) * 3 + 2];
                const float ct = cosf(0.5f * th), st = sinf(0.5f * th);
                const float am = -0.5f * (phi + om);
                const float ad =  0.5f * (phi - om);
                const float emr = cosf(am), emi = sinf(am);
                const float edr = cosf(ad), edi = sinf(ad);
                const float u00r =  emr * ct, u00i =  emi * ct;
                const float u01r = -edr * st, u01i = -edi * st;
                const float u10r =  edr * st, u10i = -edi * st;
                const float u11r =  emr * ct, u11i = -emi * ct;
                const int m = 1 << (3 - w);
#pragma unroll
                for (int i = 0; i < DIM; ++i) {
                    if (i & m) continue;
                    const int j = i | m;
                    const float ar = re[i], ai = im[i], br = re[j], bi = im[j];
                    re[i] = u00r * ar - u00i * ai + u01r * br - u01i * bi;
                    im[i] = u00r * ai + u00i * ar + u01r * bi + u01i * br;
                    re[j] = u10r * ar - u10i * ai + u11r * br - u11i * bi;
                    im[j] = u10r * ai + u10i * ar + u11r * bi + u11i * br;
                }
            }
            const int r = (l % (NQ - 1)) + 1;
            for (int w = 0; w < NQ; ++w) {
                const int t = (w + r) % NQ;
                const int cm = 1 << (3 - w);
                const int tm = 1 << (3 - t);
#pragma unroll
                for (int i = 0; i < DIM; ++i) {
                    if ((i & cm) && !(i & tm)) {
                        const int j = i | tm;
                        float tr = re[i]; re[i] = re[j]; re[j] = tr;
                        float ti = im[i]; im[i] = im[j]; im[j] = ti;
                    }
                }
            }
        }

        float p[DIM];
#pragma unroll
        for (int i = 0; i < DIM; ++i) p[i] = re[i] * re[i] + im[i] * im[i];
        for (int w = 0; w < NQ; ++w) {
            const int m = 1 << (3 - w);
            float ev = 0.f;
#pragma unroll
            for (int i = 0; i < DIM; ++i) ev += (i & m) ? -p[i] : p[i];
            sevs[w] = ev;
        }
    }
    __syncthreads();

    if (tid < SPB) {
        const int c = (slice0 & 255) + tid;
        const float acc = sevs[0] * proj_w[c * NQ + 0] + sevs[1] * proj_w[c * NQ + 1] +
                          sevs[2] * proj_w[c * NQ + 2] + sevs[3] * proj_w[c * NQ + 3] +
                          proj_b[c];
        sgate[tid] = 1.f + 1.f / (1.f + expf(-acc));
    }
    __syncthreads();

    // scale the block's 4 slices; nt loads + nt stores (pure stream, no reuse)
    for (int s = 0; s < SPB; ++s) {
        const float gt = sgate[s];
        const floatx4* x4 = (const floatx4*)(x + (size_t)(slice0 + s) * HW);
        floatx4* o4 = (floatx4*)(out + (size_t)(slice0 + s) * HW);
        floatx4 v[16];
#pragma unroll
        for (int k = 0; k < 16; ++k) v[k] = __builtin_nontemporal_load(&x4[tid + k * 256]);
#pragma unroll
        for (int k = 0; k < 16; ++k) {
            v[k] *= gt;
            __builtin_nontemporal_store(v[k], &o4[tid + k * 256]);
        }
    }
}

extern "C" void kernel_launch(void* const* d_in, const int* in_sizes, int n_in,
                              void* d_out, int out_size, void* d_ws, size_t ws_size,
                              hipStream_t stream) {
    const float* x      = (const float*)d_in[0];
    const float* enc_w  = (const float*)d_in[1];
    const float* enc_b  = (const float*)d_in[2];
    const float* qw     = (const float*)d_in[3];
    const float* proj_w = (const float*)d_in[4];
    const float* proj_b = (const float*)d_in[5];
    float* out = (float*)d_out;
    float* pooled = (float*)d_ws;             // [16*256]

    pool_kernel<<<BATCH * CH, 256, 0, stream>>>(x, pooled);
    fused_gate_scale<<<NBLK, 256, 0, stream>>>(x, enc_w, enc_b, qw,
                                               proj_w, proj_b, pooled, out);
}